// Round 7
// baseline (496.788 us; speedup 1.0000x reference)
//
#include <hip/hip_runtime.h>

#define BB 64
#define SS 2048
#define FF 256
#define CC 32

typedef unsigned u32x2 __attribute__((ext_vector_type(2)));

// Two-result permlane swaps (builtin returns {vdst, vsrc} in distinct regs).
__device__ __forceinline__ void plswap16(int a_in, int& x, int& y) {
#if __has_builtin(__builtin_amdgcn_permlane16_swap)
    u32x2 r = __builtin_amdgcn_permlane16_swap((unsigned)a_in, (unsigned)a_in, false, false);
    x = (int)r[0]; y = (int)r[1];
#else
    int xx = a_in, yy;
    asm volatile("v_mov_b32 %0, %1" : "=v"(yy) : "v"(a_in));
    asm volatile("v_permlane16_swap_b32 %0, %1" : "+v"(xx), "+v"(yy));
    x = xx; y = yy;
#endif
}
__device__ __forceinline__ void plswap32(int a_in, int& x, int& y) {
#if __has_builtin(__builtin_amdgcn_permlane32_swap)
    u32x2 r = __builtin_amdgcn_permlane32_swap((unsigned)a_in, (unsigned)a_in, false, false);
    x = (int)r[0]; y = (int)r[1];
#else
    int xx = a_in, yy;
    asm volatile("v_mov_b32 %0, %1" : "=v"(yy) : "v"(a_in));
    asm volatile("v_permlane32_swap_b32 %0, %1" : "+v"(xx), "+v"(yy));
    x = xx; y = yy;
#endif
}

// Single-instruction DPP row-rotate (foldable into consumer VALU by LLVM).
#if __has_builtin(__builtin_amdgcn_mov_dpp)
#define ROT1(d, s, K) d = __builtin_amdgcn_mov_dpp(s, 0x120 + K, 0xF, 0xF, false)
#else
#define ROT1(d, s, K) d = __builtin_amdgcn_update_dpp(s, s, 0x120 + K, 0xF, 0xF, false)
#endif
#define ROTALL(arr, s) \
    arr[0] = s;        \
    ROT1(arr[1], s, 1);  ROT1(arr[2], s, 2);  ROT1(arr[3], s, 3);  \
    ROT1(arr[4], s, 4);  ROT1(arr[5], s, 5);  ROT1(arr[6], s, 6);  \
    ROT1(arr[7], s, 7);  ROT1(arr[8], s, 8);  ROT1(arr[9], s, 9);  \
    ROT1(arr[10], s, 10); ROT1(arr[11], s, 11); ROT1(arr[12], s, 12); \
    ROT1(arr[13], s, 13); ROT1(arr[14], s, 14); ROT1(arr[15], s, 15)

__device__ __forceinline__ float fmax3_(float a, float b, float c) { return fmaxf(fmaxf(a, b), c); }

// ---------------------------------------------------------------------------
// Kernel 1: emissions GEMM — UNCHANGED (bit-exact; ~45 us).
// ---------------------------------------------------------------------------
__global__ __launch_bounds__(256) void emis_kernel(const float* __restrict__ X,
                                                   const float* __restrict__ W,
                                                   const float* __restrict__ bias,
                                                   float* __restrict__ em) {
    __shared__ __align__(16) float xs[64 * 260];
    __shared__ __align__(16) float wsh[32 * 260];
    const int tid = threadIdx.x;
    const long rowbase = (long)blockIdx.x * 64;

    const float4* Xg = (const float4*)(X + rowbase * FF);
#pragma unroll
    for (int i = 0; i < 16; ++i) {
        int idx = tid + i * 256;
        int r = idx >> 6, c4 = idx & 63;
        *(float4*)&xs[r * 260 + c4 * 4] = Xg[idx];
    }
    const float4* Wg = (const float4*)W;
#pragma unroll
    for (int i = 0; i < 8; ++i) {
        int idx = tid + i * 256;
        int r = idx >> 6, c4 = idx & 63;
        *(float4*)&wsh[r * 260 + c4 * 4] = Wg[idx];
    }
    __syncthreads();

    const int rp = tid >> 3;
    const int cg = (tid & 7) * 4;
    const int r0 = rp * 2, r1 = rp * 2 + 1;
    float acc0[4] = {0.f, 0.f, 0.f, 0.f};
    float acc1[4] = {0.f, 0.f, 0.f, 0.f};

#pragma unroll 4
    for (int k = 0; k < 256; k += 4) {
        float4 xa = *(const float4*)&xs[r0 * 260 + k];
        float4 xb = *(const float4*)&xs[r1 * 260 + k];
#pragma unroll
        for (int jj = 0; jj < 4; ++jj) {
            float4 w = *(const float4*)&wsh[(cg + jj) * 260 + k];
            acc0[jj] = fmaf(xa.x, w.x, acc0[jj]);
            acc0[jj] = fmaf(xa.y, w.y, acc0[jj]);
            acc0[jj] = fmaf(xa.z, w.z, acc0[jj]);
            acc0[jj] = fmaf(xa.w, w.w, acc0[jj]);
            acc1[jj] = fmaf(xb.x, w.x, acc1[jj]);
            acc1[jj] = fmaf(xb.y, w.y, acc1[jj]);
            acc1[jj] = fmaf(xb.z, w.z, acc1[jj]);
            acc1[jj] = fmaf(xb.w, w.w, acc1[jj]);
        }
    }
#pragma unroll
    for (int jj = 0; jj < 4; ++jj) {
        float bj = bias[cg + jj];
        em[(rowbase + r0) * CC + cg + jj] = acc0[jj] + bj;
        em[(rowbase + r1) * CC + cg + jj] = acc1[jj] + bj;
    }
}

// ---------------------------------------------------------------------------
// Kernel 2: forward alpha chain, TWO batches per wave (one per 32-lane group).
// Lane l: bq = l>>5 (batch slot), j = l&31 (state). One permlane16_swap per
// step exposes the partner 16-row; 32 DPP-rotated adds enumerate all 32
// candidates for this lane's j; v_max3 tree -> gv; a = gv + e. No swap32.
// e staged via LDS double buffer (global float4 loads one 32-step chunk
// ahead), hand-hoisted into regs 8 steps at a time (one lgkm wait / 8 steps).
// Alpha stored in-place over em (same values/order as r6 -> bit-identical).
// ---------------------------------------------------------------------------
__global__ __launch_bounds__(64, 1) void viterbi_fwd2(float* __restrict__ em,
                                                      const float* __restrict__ T,
                                                      const float* __restrict__ startT,
                                                      const float* __restrict__ endT,
                                                      float* __restrict__ out) {
    __shared__ float ebuf[2][2][1024];     // [buf][bq][step*32+state]
    const int l = threadIdx.x;
    const int bq = l >> 5;
    const int j = l & 31;
    const int b = (blockIdx.x << 1) | bq;

    // probe swap16: which output holds the partner row, and its index map
    int p0, p1;
    plswap16(j, p0, p1);
    const bool swx = (p0 != j);            // per-lane: x is the swapped-row reg
    const int po = swx ? p0 : p1;          // partner-row probe value (j^16)
    int mkO[16], mkS[16];
    ROTALL(mkO, j);                        // own-row indices delivered by rot k
    ROTALL(mkS, po);                       // partner-row indices delivered by rot k

    float TiO[16], TiS[16];
#pragma unroll
    for (int k = 0; k < 16; ++k) {
        TiO[k] = T[mkO[k] * CC + j];
        TiS[k] = T[mkS[k] * CC + j];
    }

    float* eb = em + (long)b * SS * CC;    // this batch's emissions -> alphas
    const float4* ebv = (const float4*)eb;

    // stage chunk 0, issue chunk-1 loads
    float4 st[8];
#pragma unroll
    for (int v = 0; v < 8; ++v) st[v] = ebv[v * 32 + j];
#pragma unroll
    for (int v = 0; v < 8; ++v) *(float4*)&ebuf[0][bq][(v * 32 + j) * 4] = st[v];
#pragma unroll
    for (int v = 0; v < 8; ++v) st[v] = ebv[256 + v * 32 + j];

    float a = 0.0f;
    const float stj = startT[j];

    auto step = [&](float e) {
        int x, y;
        plswap16(__float_as_int(a), x, y);
        int o = swx ? x : y;               // partner-row alphas
        int rO[16], rS[16];
        ROTALL(rO, __float_as_int(a));
        ROTALL(rS, o);
        float s0[16], s1[16];
#pragma unroll
        for (int k = 0; k < 16; ++k) {
            s0[k] = __int_as_float(rO[k]) + TiO[k];
            s1[k] = __int_as_float(rS[k]) + TiS[k];
        }
        // exact max over 32 (tree shape irrelevant for float max)
        float v0 = fmax3_(s0[0], s0[1], s0[2]);
        float v1 = fmax3_(s0[3], s0[4], s0[5]);
        float v2 = fmax3_(s0[6], s0[7], s0[8]);
        float v3 = fmax3_(s0[9], s0[10], s0[11]);
        float v4 = fmax3_(s0[12], s0[13], s0[14]);
        float v5 = fmax3_(s0[15], s1[0], s1[1]);
        float v6 = fmax3_(s1[2], s1[3], s1[4]);
        float v7 = fmax3_(s1[5], s1[6], s1[7]);
        float v8 = fmax3_(s1[8], s1[9], s1[10]);
        float v9 = fmax3_(s1[11], s1[12], s1[13]);
        float w0 = fmax3_(v0, v1, v2);
        float w1 = fmax3_(v3, v4, v5);
        float w2 = fmax3_(v6, v7, v8);
        float w3 = fmax3_(v9, s1[14], s1[15]);
        float gv = fmaxf(fmaxf(w0, w1), fmaxf(w2, w3));
        a = gv + e;
    };

    for (int m = 0; m < 64; ++m) {
        if (m > 0) {
            float* wbuf = &ebuf[m & 1][bq][0];
#pragma unroll
            for (int v = 0; v < 8; ++v) *(float4*)&wbuf[(v * 32 + j) * 4] = st[v];
            if (m < 63) {
#pragma unroll
                for (int v = 0; v < 8; ++v) st[v] = ebv[(m + 1) * 256 + v * 32 + j];
            }
        }
        const float* buf = &ebuf[m & 1][bq][0];
        float* aw = eb + (long)m * 1024 + j;   // alpha store base for this chunk
#pragma unroll
        for (int g8 = 0; g8 < 4; ++g8) {
            float er[8];
#pragma unroll
            for (int v = 0; v < 8; ++v) er[v] = buf[(g8 * 8 + v) * 32 + j];
#pragma unroll
            for (int v = 0; v < 8; ++v) {
                if (m == 0 && g8 == 0 && v == 0) {
                    a = stj + er[0];           // alpha_0
                } else {
                    step(er[v]);
                }
                aw[(g8 * 8 + v) * 32] = a;
            }
        }
    }

    // final: best_score + last tag (tie -> lowest j), per 32-lane group
    float v = a + endT[j];
    int idx = j;
#pragma unroll
    for (int d = 1; d <= 16; d <<= 1) {
        float ovv = __shfl_xor(v, d);
        int   oii = __shfl_xor(idx, d);
        bool c = (ovv > v) || (ovv == v && oii < idx);
        v = c ? ovv : v;
        idx = c ? oii : idx;
    }
    if (j == 0) {
        out[b] = v;
        out[BB + (long)b * SS + (SS - 1)] = (float)idx;
    }
}

// ---------------------------------------------------------------------------
// Kernel 3: bp_compose — UNCHANGED from r6 (recomputes bp from stored alphas,
// exact argmax semantics, packs, composes chunk LUT G). 2048 parallel waves.
// ---------------------------------------------------------------------------
__global__ __launch_bounds__(64, 2) void bp_compose(const float* __restrict__ alpha,
                                                    const float* __restrict__ T,
                                                    unsigned* __restrict__ bp,
                                                    unsigned char* __restrict__ G) {
    const int l = threadIdx.x;
    const int j = l & 31;
    const int h = l >> 5;
    const int b = blockIdx.x >> 5;
    const int k = blockIdx.x & 31;

    int p0, p1;
    plswap16(j, p0, p1);
    const bool c16 = (((p0 >> 4) & 1) == h);
    const int pm = c16 ? p0 : p1;
    int mk[16];
    ROTALL(mk, pm);
    int q0, q1;
    plswap32(l, q0, q1);
    const bool pick0 = (q0 == (l ^ 32));

    float Ti[16];
    unsigned Bk[16];
#pragma unroll
    for (int kk = 0; kk < 16; ++kk) {
        Ti[kk] = T[mk[kk] * CC + j];
        Bk[kk] = 1u << mk[kk];
    }

    const float* A = alpha + (long)b * SS * CC;
    const int kk0 = k << 6;

    float aq[8];
#pragma unroll
    for (int v = 0; v < 8; ++v) aq[v] = A[(kk0 + v) * CC + j];

    unsigned sr[16];
#pragma unroll
    for (int p = 0; p < 16; ++p) sr[p] = 0u;

#pragma unroll
    for (int g8 = 0; g8 < 8; ++g8) {
#pragma unroll
        for (int v = 0; v < 8; ++v) {
            const int u = g8 * 8 + v;
            float av = aq[v];
            if (g8 < 7) aq[v] = A[(kk0 + (g8 + 1) * 8 + v) * CC + j];

            int x, y;
            plswap16(__float_as_int(av), x, y);
            int base = c16 ? x : y;
            int rot[16];
            ROTALL(rot, base);
            float s[16];
#pragma unroll
            for (int kk = 0; kk < 16; ++kk) s[kk] = __int_as_float(rot[kk]) + Ti[kk];

            float m0 = fmax3_(s[0], s[1], s[2]);
            float m1 = fmax3_(s[3], s[4], s[5]);
            float m2 = fmax3_(s[6], s[7], s[8]);
            float m3 = fmax3_(s[9], s[10], s[11]);
            float m4 = fmax3_(s[12], s[13], s[14]);
            float mv = fmaxf(fmax3_(m0, m1, m2), fmax3_(m3, m4, s[15]));

            int xm, ym;
            plswap32(__float_as_int(mv), xm, ym);
            float ov = __int_as_float(pick0 ? xm : ym);
            float gv = fmaxf(mv, ov);

            unsigned c0 = (s[0] == gv) ? Bk[0] : 0u,   c1 = (s[1] == gv) ? Bk[1] : 0u;
            unsigned c2 = (s[2] == gv) ? Bk[2] : 0u,   c3 = (s[3] == gv) ? Bk[3] : 0u;
            unsigned c4 = (s[4] == gv) ? Bk[4] : 0u,   c5 = (s[5] == gv) ? Bk[5] : 0u;
            unsigned c6 = (s[6] == gv) ? Bk[6] : 0u,   c7 = (s[7] == gv) ? Bk[7] : 0u;
            unsigned c8 = (s[8] == gv) ? Bk[8] : 0u,   c9 = (s[9] == gv) ? Bk[9] : 0u;
            unsigned c10 = (s[10] == gv) ? Bk[10] : 0u, c11 = (s[11] == gv) ? Bk[11] : 0u;
            unsigned c12 = (s[12] == gv) ? Bk[12] : 0u, c13 = (s[13] == gv) ? Bk[13] : 0u;
            unsigned c14 = (s[14] == gv) ? Bk[14] : 0u, c15 = (s[15] == gv) ? Bk[15] : 0u;
            unsigned msk = ((c0 | c1 | c2) | (c3 | c4 | c5)) |
                           ((c6 | c7 | c8) | (c9 | c10 | c11)) |
                           ((c12 | c13 | c14) | c15);

            int xk, yk;
            plswap32((int)msk, xk, yk);
            unsigned om = (unsigned)(pick0 ? xk : yk);
            int wi = __builtin_ctz(msk | om);

            if (u == 63) {
                if (kk0 + 63 == SS - 1) wi = j;
            }
            sr[u >> 2] |= (unsigned)wi << ((u & 3) * 8);
        }
    }

#pragma unroll
    for (int p = 0; p < 16; ++p)
        bp[((unsigned)(16 * k + p) * BB + b) * CC + j] = sr[p];

    int g = j;
#pragma unroll
    for (int rel = 63; rel >= 0; --rel) {
        unsigned dw = (unsigned)__builtin_amdgcn_ds_bpermute((g | (l & 32)) << 2,
                                                             (int)sr[rel >> 2]);
        g = (int)((dw >> ((rel & 3) * 8)) & 31u);
    }
    G[(b * 32 + k) * 32 + j] = (unsigned char)g;
}

// ---------------------------------------------------------------------------
// bt_scan / bt_emit — UNCHANGED (proven).
// ---------------------------------------------------------------------------
__global__ __launch_bounds__(64) void bt_scan(const unsigned char* __restrict__ G,
                                              const float* __restrict__ out,
                                              int* __restrict__ tagB) {
    __shared__ unsigned char Gs[64 * 32 * 32];
    const int l = threadIdx.x;
    const float4* Gg = (const float4*)G;
    float4* Gls = (float4*)Gs;
#pragma unroll
    for (int i = 0; i < 64; ++i) Gls[l + i * 64] = Gg[l + i * 64];
    __syncthreads();

    const int b = l;
    int cur = (int)out[BB + (long)b * SS + (SS - 1)];
    for (int k = 31; k >= 0; --k) {
        cur = Gs[(b * 32 + k) * 32 + cur];
        tagB[b * 32 + k] = cur;
    }
}

__global__ __launch_bounds__(64) void bt_emit(const unsigned* __restrict__ bp,
                                              const int* __restrict__ tagB,
                                              float* __restrict__ out) {
    const int l = threadIdx.x;
    const int b = blockIdx.x >> 5;
    const int k = blockIdx.x & 31;

    unsigned sr[16];
#pragma unroll
    for (int p = 0; p < 16; ++p) sr[p] = bp[((unsigned)(16 * k + p) * BB + b) * CC + (l & 31)];

    int start = (k == 31) ? (int)out[BB + (long)b * SS + (SS - 1)]
                          : tagB[b * 32 + k + 1];
    int g = start, cap = start;
#pragma unroll
    for (int rel = 63; rel >= 0; --rel) {
        unsigned dw = (unsigned)__builtin_amdgcn_ds_bpermute((g | (l & 32)) << 2,
                                                             (int)sr[rel >> 2]);
        g = (int)((dw >> ((rel & 3) * 8)) & 31u);
        cap = (l == rel) ? g : cap;
    }
    out[BB + (long)b * SS + k * 64 + l] = (float)cap;
}

// ---------------------------------------------------------------------------
extern "C" void kernel_launch(void* const* d_in, const int* in_sizes, int n_in,
                              void* d_out, int out_size, void* d_ws, size_t ws_size,
                              hipStream_t stream) {
    const float* X      = (const float*)d_in[0];
    const float* W      = (const float*)d_in[1];
    const float* bias   = (const float*)d_in[2];
    const float* T      = (const float*)d_in[3];
    const float* startT = (const float*)d_in[4];
    const float* endT   = (const float*)d_in[5];
    float* out = (float*)d_out;

    float*    em = (float*)d_ws;                                        // 16 MB (e -> alpha in-place)
    unsigned* bp = (unsigned*)((char*)d_ws + (size_t)BB * SS * CC * 4); // 4 MB @ 16 MB
    unsigned char* G    = (unsigned char*)d_ws + (20u << 20);           // 64 KB @ 20 MB
    int*           tagB = (int*)((char*)d_ws + (20u << 20) + 65536);    // 8 KB

    emis_kernel<<<(BB * SS) / 64, 256, 0, stream>>>(X, W, bias, em);
    viterbi_fwd2<<<BB / 2, 64, 0, stream>>>(em, T, startT, endT, out);
    bp_compose<<<BB * 32, 64, 0, stream>>>(em, T, bp, G);
    bt_scan<<<1, 64, 0, stream>>>(G, out, tagB);
    bt_emit<<<BB * 32, 64, 0, stream>>>(bp, tagB, out);
}

// Round 8
// 347.732 us; speedup vs baseline: 1.4287x; 1.4287x over previous
//
#include <hip/hip_runtime.h>

#define BB 64
#define SS 2048
#define FF 256
#define CC 32

typedef unsigned u32x2 __attribute__((ext_vector_type(2)));

// Two-result permlane swaps (builtin returns {vdst, vsrc} in distinct regs).
__device__ __forceinline__ void plswap16(int a_in, int& x, int& y) {
#if __has_builtin(__builtin_amdgcn_permlane16_swap)
    u32x2 r = __builtin_amdgcn_permlane16_swap((unsigned)a_in, (unsigned)a_in, false, false);
    x = (int)r[0]; y = (int)r[1];
#else
    int xx = a_in, yy;
    asm volatile("v_mov_b32 %0, %1" : "=v"(yy) : "v"(a_in));
    asm volatile("v_permlane16_swap_b32 %0, %1" : "+v"(xx), "+v"(yy));
    x = xx; y = yy;
#endif
}
__device__ __forceinline__ void plswap32(int a_in, int& x, int& y) {
#if __has_builtin(__builtin_amdgcn_permlane32_swap)
    u32x2 r = __builtin_amdgcn_permlane32_swap((unsigned)a_in, (unsigned)a_in, false, false);
    x = (int)r[0]; y = (int)r[1];
#else
    int xx = a_in, yy;
    asm volatile("v_mov_b32 %0, %1" : "=v"(yy) : "v"(a_in));
    asm volatile("v_permlane32_swap_b32 %0, %1" : "+v"(xx), "+v"(yy));
    x = xx; y = yy;
#endif
}

// Single-instruction DPP row-rotate (foldable into consumer VALU by LLVM).
#if __has_builtin(__builtin_amdgcn_mov_dpp)
#define ROT1(d, s, K) d = __builtin_amdgcn_mov_dpp(s, 0x120 + K, 0xF, 0xF, false)
#else
#define ROT1(d, s, K) d = __builtin_amdgcn_update_dpp(s, s, 0x120 + K, 0xF, 0xF, false)
#endif
#define ROTALL(arr, s) \
    arr[0] = s;        \
    ROT1(arr[1], s, 1);  ROT1(arr[2], s, 2);  ROT1(arr[3], s, 3);  \
    ROT1(arr[4], s, 4);  ROT1(arr[5], s, 5);  ROT1(arr[6], s, 6);  \
    ROT1(arr[7], s, 7);  ROT1(arr[8], s, 8);  ROT1(arr[9], s, 9);  \
    ROT1(arr[10], s, 10); ROT1(arr[11], s, 11); ROT1(arr[12], s, 12); \
    ROT1(arr[13], s, 13); ROT1(arr[14], s, 14); ROT1(arr[15], s, 15)

__device__ __forceinline__ float fmax3_(float a, float b, float c) { return fmaxf(fmaxf(a, b), c); }

// ---------------------------------------------------------------------------
// Kernel 1: emissions GEMM — UNCHANGED (bit-exact; ~45 us).
// ---------------------------------------------------------------------------
__global__ __launch_bounds__(256) void emis_kernel(const float* __restrict__ X,
                                                   const float* __restrict__ W,
                                                   const float* __restrict__ bias,
                                                   float* __restrict__ em) {
    __shared__ __align__(16) float xs[64 * 260];
    __shared__ __align__(16) float wsh[32 * 260];
    const int tid = threadIdx.x;
    const long rowbase = (long)blockIdx.x * 64;

    const float4* Xg = (const float4*)(X + rowbase * FF);
#pragma unroll
    for (int i = 0; i < 16; ++i) {
        int idx = tid + i * 256;
        int r = idx >> 6, c4 = idx & 63;
        *(float4*)&xs[r * 260 + c4 * 4] = Xg[idx];
    }
    const float4* Wg = (const float4*)W;
#pragma unroll
    for (int i = 0; i < 8; ++i) {
        int idx = tid + i * 256;
        int r = idx >> 6, c4 = idx & 63;
        *(float4*)&wsh[r * 260 + c4 * 4] = Wg[idx];
    }
    __syncthreads();

    const int rp = tid >> 3;
    const int cg = (tid & 7) * 4;
    const int r0 = rp * 2, r1 = rp * 2 + 1;
    float acc0[4] = {0.f, 0.f, 0.f, 0.f};
    float acc1[4] = {0.f, 0.f, 0.f, 0.f};

#pragma unroll 4
    for (int k = 0; k < 256; k += 4) {
        float4 xa = *(const float4*)&xs[r0 * 260 + k];
        float4 xb = *(const float4*)&xs[r1 * 260 + k];
#pragma unroll
        for (int jj = 0; jj < 4; ++jj) {
            float4 w = *(const float4*)&wsh[(cg + jj) * 260 + k];
            acc0[jj] = fmaf(xa.x, w.x, acc0[jj]);
            acc0[jj] = fmaf(xa.y, w.y, acc0[jj]);
            acc0[jj] = fmaf(xa.z, w.z, acc0[jj]);
            acc0[jj] = fmaf(xa.w, w.w, acc0[jj]);
            acc1[jj] = fmaf(xb.x, w.x, acc1[jj]);
            acc1[jj] = fmaf(xb.y, w.y, acc1[jj]);
            acc1[jj] = fmaf(xb.z, w.z, acc1[jj]);
            acc1[jj] = fmaf(xb.w, w.w, acc1[jj]);
        }
    }
#pragma unroll
    for (int jj = 0; jj < 4; ++jj) {
        float bj = bias[cg + jj];
        em[(rowbase + r0) * CC + cg + jj] = acc0[jj] + bj;
        em[(rowbase + r1) * CC + cg + jj] = acc1[jj] + bj;
    }
}

// ---------------------------------------------------------------------------
// Kernel 2: forward alpha chain — r6 structure (64 blocks x 1 wave, half-split
// i-range, 17 cross-lane ops/step = near information floor), but emissions
// delivered via an 8-deep GLOBAL register queue (no LDS at all): loads issued
// 8 steps (~2000 cyc) ahead -> vmcnt satisfied, stall bucket removed.
// Alpha stored in-place over em (loads read t+8, stores write t -> no hazard).
// Arithmetic bit-identical to r6.
// ---------------------------------------------------------------------------
__global__ __launch_bounds__(64, 1) void viterbi_fwd3(float* __restrict__ em,
                                                      const float* __restrict__ T,
                                                      const float* __restrict__ startT,
                                                      const float* __restrict__ endT,
                                                      float* __restrict__ out) {
    const int l = threadIdx.x;
    const int b = blockIdx.x;
    const int j = l & 31;
    const int h = l >> 5;

    // probe permlane16_swap orientation
    int p0, p1;
    plswap16(j, p0, p1);
    const bool c16 = (((p0 >> 4) & 1) == h);
    const int pm = c16 ? p0 : p1;
    int mk[16];
    ROTALL(mk, pm);
    // probe permlane32_swap orientation
    int q0, q1;
    plswap32(l, q0, q1);
    const bool pick0 = (q0 == (l ^ 32));

    float Ti[16];
#pragma unroll
    for (int k = 0; k < 16; ++k) Ti[k] = T[mk[k] * CC + j];

    float* eb = em + (long)b * SS * CC;

    // 8-deep emission prefetch queue (e[t] lives in eq[t&7])
    float eq[8];
#pragma unroll
    for (int v = 0; v < 8; ++v) eq[v] = eb[v * 32 + j];

    float a = startT[j] + eq[0];           // alpha_0
    eb[j] = a;                             // store alpha_0 (dup lanes: same addr+data)
    eq[0] = eb[8 * 32 + j];                // refill slot 0 with e[8]

    auto step = [&](float e) {
        int x, y;
        plswap16(__float_as_int(a), x, y);
        int base = c16 ? x : y;
        int rot[16];
        ROTALL(rot, base);
        float s[16];
#pragma unroll
        for (int k = 0; k < 16; ++k) s[k] = __int_as_float(rot[k]) + Ti[k];

        float m0 = fmax3_(s[0], s[1], s[2]);
        float m1 = fmax3_(s[3], s[4], s[5]);
        float m2 = fmax3_(s[6], s[7], s[8]);
        float m3 = fmax3_(s[9], s[10], s[11]);
        float m4 = fmax3_(s[12], s[13], s[14]);
        float mv = fmaxf(fmax3_(m0, m1, m2), fmax3_(m3, m4, s[15]));

        int xm, ym;
        plswap32(__float_as_int(mv), xm, ym);
        float ov = __int_as_float(pick0 ? xm : ym);
        float gv = fmaxf(mv, ov);

        a = gv + e;
    };

    int t = 1;
    // main: 254 groups of 8 -> t = 1..2032 (loads e[t+8] <= e[2040])
    for (int g = 0; g < 254; ++g) {
#pragma unroll
        for (int u = 0; u < 8; ++u) {
            step(eq[t & 7]);
            eb[t * 32 + j] = a;
            eq[t & 7] = eb[(t + 8) * 32 + j];
            ++t;
        }
    }
    // t = 2033..2039 (loads e[2041..2047])
#pragma unroll
    for (int u = 0; u < 7; ++u) {
        step(eq[t & 7]);
        eb[t * 32 + j] = a;
        eq[t & 7] = eb[(t + 8) * 32 + j];
        ++t;
    }
    // t = 2040..2047 (no loads)
#pragma unroll
    for (int u = 0; u < 8; ++u) {
        step(eq[t & 7]);
        eb[t * 32 + j] = a;
        ++t;
    }

    // final: best_score + last tag (tie -> lowest j)
    float v = a + endT[j];
    int idx = j;
#pragma unroll
    for (int d = 1; d <= 16; d <<= 1) {
        float ovv = __shfl_xor(v, d);
        int   oii = __shfl_xor(idx, d);
        bool c = (ovv > v) || (ovv == v && oii < idx);
        v = c ? ovv : v;
        idx = c ? oii : idx;
    }
    if (l == 0) {
        out[b] = v;
        out[BB + (long)b * SS + (SS - 1)] = (float)idx;
    }
}

// ---------------------------------------------------------------------------
// Kernel 3: bp_compose — UNCHANGED from r6 (recomputes bp from stored alphas,
// exact argmax semantics, packs, composes chunk LUT G). 2048 parallel waves.
// ---------------------------------------------------------------------------
__global__ __launch_bounds__(64, 2) void bp_compose(const float* __restrict__ alpha,
                                                    const float* __restrict__ T,
                                                    unsigned* __restrict__ bp,
                                                    unsigned char* __restrict__ G) {
    const int l = threadIdx.x;
    const int j = l & 31;
    const int h = l >> 5;
    const int b = blockIdx.x >> 5;
    const int k = blockIdx.x & 31;

    int p0, p1;
    plswap16(j, p0, p1);
    const bool c16 = (((p0 >> 4) & 1) == h);
    const int pm = c16 ? p0 : p1;
    int mk[16];
    ROTALL(mk, pm);
    int q0, q1;
    plswap32(l, q0, q1);
    const bool pick0 = (q0 == (l ^ 32));

    float Ti[16];
    unsigned Bk[16];
#pragma unroll
    for (int kk = 0; kk < 16; ++kk) {
        Ti[kk] = T[mk[kk] * CC + j];
        Bk[kk] = 1u << mk[kk];
    }

    const float* A = alpha + (long)b * SS * CC;
    const int kk0 = k << 6;

    float aq[8];
#pragma unroll
    for (int v = 0; v < 8; ++v) aq[v] = A[(kk0 + v) * CC + j];

    unsigned sr[16];
#pragma unroll
    for (int p = 0; p < 16; ++p) sr[p] = 0u;

#pragma unroll
    for (int g8 = 0; g8 < 8; ++g8) {
#pragma unroll
        for (int v = 0; v < 8; ++v) {
            const int u = g8 * 8 + v;
            float av = aq[v];
            if (g8 < 7) aq[v] = A[(kk0 + (g8 + 1) * 8 + v) * CC + j];

            int x, y;
            plswap16(__float_as_int(av), x, y);
            int base = c16 ? x : y;
            int rot[16];
            ROTALL(rot, base);
            float s[16];
#pragma unroll
            for (int kk = 0; kk < 16; ++kk) s[kk] = __int_as_float(rot[kk]) + Ti[kk];

            float m0 = fmax3_(s[0], s[1], s[2]);
            float m1 = fmax3_(s[3], s[4], s[5]);
            float m2 = fmax3_(s[6], s[7], s[8]);
            float m3 = fmax3_(s[9], s[10], s[11]);
            float m4 = fmax3_(s[12], s[13], s[14]);
            float mv = fmaxf(fmax3_(m0, m1, m2), fmax3_(m3, m4, s[15]));

            int xm, ym;
            plswap32(__float_as_int(mv), xm, ym);
            float ov = __int_as_float(pick0 ? xm : ym);
            float gv = fmaxf(mv, ov);

            unsigned c0 = (s[0] == gv) ? Bk[0] : 0u,   c1 = (s[1] == gv) ? Bk[1] : 0u;
            unsigned c2 = (s[2] == gv) ? Bk[2] : 0u,   c3 = (s[3] == gv) ? Bk[3] : 0u;
            unsigned c4 = (s[4] == gv) ? Bk[4] : 0u,   c5 = (s[5] == gv) ? Bk[5] : 0u;
            unsigned c6 = (s[6] == gv) ? Bk[6] : 0u,   c7 = (s[7] == gv) ? Bk[7] : 0u;
            unsigned c8 = (s[8] == gv) ? Bk[8] : 0u,   c9 = (s[9] == gv) ? Bk[9] : 0u;
            unsigned c10 = (s[10] == gv) ? Bk[10] : 0u, c11 = (s[11] == gv) ? Bk[11] : 0u;
            unsigned c12 = (s[12] == gv) ? Bk[12] : 0u, c13 = (s[13] == gv) ? Bk[13] : 0u;
            unsigned c14 = (s[14] == gv) ? Bk[14] : 0u, c15 = (s[15] == gv) ? Bk[15] : 0u;
            unsigned msk = ((c0 | c1 | c2) | (c3 | c4 | c5)) |
                           ((c6 | c7 | c8) | (c9 | c10 | c11)) |
                           ((c12 | c13 | c14) | c15);

            int xk, yk;
            plswap32((int)msk, xk, yk);
            unsigned om = (unsigned)(pick0 ? xk : yk);
            int wi = __builtin_ctz(msk | om);

            if (u == 63) {
                if (kk0 + 63 == SS - 1) wi = j;
            }
            sr[u >> 2] |= (unsigned)wi << ((u & 3) * 8);
        }
    }

#pragma unroll
    for (int p = 0; p < 16; ++p)
        bp[((unsigned)(16 * k + p) * BB + b) * CC + j] = sr[p];

    int g = j;
#pragma unroll
    for (int rel = 63; rel >= 0; --rel) {
        unsigned dw = (unsigned)__builtin_amdgcn_ds_bpermute((g | (l & 32)) << 2,
                                                             (int)sr[rel >> 2]);
        g = (int)((dw >> ((rel & 3) * 8)) & 31u);
    }
    G[(b * 32 + k) * 32 + j] = (unsigned char)g;
}

// ---------------------------------------------------------------------------
// bt_scan / bt_emit — UNCHANGED (proven).
// ---------------------------------------------------------------------------
__global__ __launch_bounds__(64) void bt_scan(const unsigned char* __restrict__ G,
                                              const float* __restrict__ out,
                                              int* __restrict__ tagB) {
    __shared__ unsigned char Gs[64 * 32 * 32];
    const int l = threadIdx.x;
    const float4* Gg = (const float4*)G;
    float4* Gls = (float4*)Gs;
#pragma unroll
    for (int i = 0; i < 64; ++i) Gls[l + i * 64] = Gg[l + i * 64];
    __syncthreads();

    const int b = l;
    int cur = (int)out[BB + (long)b * SS + (SS - 1)];
    for (int k = 31; k >= 0; --k) {
        cur = Gs[(b * 32 + k) * 32 + cur];
        tagB[b * 32 + k] = cur;
    }
}

__global__ __launch_bounds__(64) void bt_emit(const unsigned* __restrict__ bp,
                                              const int* __restrict__ tagB,
                                              float* __restrict__ out) {
    const int l = threadIdx.x;
    const int b = blockIdx.x >> 5;
    const int k = blockIdx.x & 31;

    unsigned sr[16];
#pragma unroll
    for (int p = 0; p < 16; ++p) sr[p] = bp[((unsigned)(16 * k + p) * BB + b) * CC + (l & 31)];

    int start = (k == 31) ? (int)out[BB + (long)b * SS + (SS - 1)]
                          : tagB[b * 32 + k + 1];
    int g = start, cap = start;
#pragma unroll
    for (int rel = 63; rel >= 0; --rel) {
        unsigned dw = (unsigned)__builtin_amdgcn_ds_bpermute((g | (l & 32)) << 2,
                                                             (int)sr[rel >> 2]);
        g = (int)((dw >> ((rel & 3) * 8)) & 31u);
        cap = (l == rel) ? g : cap;
    }
    out[BB + (long)b * SS + k * 64 + l] = (float)cap;
}

// ---------------------------------------------------------------------------
extern "C" void kernel_launch(void* const* d_in, const int* in_sizes, int n_in,
                              void* d_out, int out_size, void* d_ws, size_t ws_size,
                              hipStream_t stream) {
    const float* X      = (const float*)d_in[0];
    const float* W      = (const float*)d_in[1];
    const float* bias   = (const float*)d_in[2];
    const float* T      = (const float*)d_in[3];
    const float* startT = (const float*)d_in[4];
    const float* endT   = (const float*)d_in[5];
    float* out = (float*)d_out;

    float*    em = (float*)d_ws;                                        // 16 MB (e -> alpha in-place)
    unsigned* bp = (unsigned*)((char*)d_ws + (size_t)BB * SS * CC * 4); // 4 MB @ 16 MB
    unsigned char* G    = (unsigned char*)d_ws + (20u << 20);           // 64 KB @ 20 MB
    int*           tagB = (int*)((char*)d_ws + (20u << 20) + 65536);    // 8 KB

    emis_kernel<<<(BB * SS) / 64, 256, 0, stream>>>(X, W, bias, em);
    viterbi_fwd3<<<BB, 64, 0, stream>>>(em, T, startT, endT, out);
    bp_compose<<<BB * 32, 64, 0, stream>>>(em, T, bp, G);
    bt_scan<<<1, 64, 0, stream>>>(G, out, tagB);
    bt_emit<<<BB * 32, 64, 0, stream>>>(bp, tagB, out);
}

// Round 9
// 307.900 us; speedup vs baseline: 1.6135x; 1.1294x over previous
//
#include <hip/hip_runtime.h>

#define BB 64
#define SS 2048
#define FF 256
#define CC 32

typedef unsigned u32x2 __attribute__((ext_vector_type(2)));

// Two-result permlane swaps (builtin returns {vdst, vsrc} in distinct regs).
__device__ __forceinline__ void plswap16(int a_in, int& x, int& y) {
#if __has_builtin(__builtin_amdgcn_permlane16_swap)
    u32x2 r = __builtin_amdgcn_permlane16_swap((unsigned)a_in, (unsigned)a_in, false, false);
    x = (int)r[0]; y = (int)r[1];
#else
    int xx = a_in, yy;
    asm volatile("v_mov_b32 %0, %1" : "=v"(yy) : "v"(a_in));
    asm volatile("v_permlane16_swap_b32 %0, %1" : "+v"(xx), "+v"(yy));
    x = xx; y = yy;
#endif
}
__device__ __forceinline__ void plswap32(int a_in, int& x, int& y) {
#if __has_builtin(__builtin_amdgcn_permlane32_swap)
    u32x2 r = __builtin_amdgcn_permlane32_swap((unsigned)a_in, (unsigned)a_in, false, false);
    x = (int)r[0]; y = (int)r[1];
#else
    int xx = a_in, yy;
    asm volatile("v_mov_b32 %0, %1" : "=v"(yy) : "v"(a_in));
    asm volatile("v_permlane32_swap_b32 %0, %1" : "+v"(xx), "+v"(yy));
    x = xx; y = yy;
#endif
}

// Single-instruction DPP row-rotate (probe/index-map use).
#if __has_builtin(__builtin_amdgcn_mov_dpp)
#define ROT1(d, s, K) d = __builtin_amdgcn_mov_dpp(s, 0x120 + K, 0xF, 0xF, false)
#else
#define ROT1(d, s, K) d = __builtin_amdgcn_update_dpp(s, s, 0x120 + K, 0xF, 0xF, false)
#endif
#define ROTALL(arr, s) \
    arr[0] = s;        \
    ROT1(arr[1], s, 1);  ROT1(arr[2], s, 2);  ROT1(arr[3], s, 3);  \
    ROT1(arr[4], s, 4);  ROT1(arr[5], s, 5);  ROT1(arr[6], s, 6);  \
    ROT1(arr[7], s, 7);  ROT1(arr[8], s, 8);  ROT1(arr[9], s, 9);  \
    ROT1(arr[10], s, 10); ROT1(arr[11], s, 11); ROT1(arr[12], s, 12); \
    ROT1(arr[13], s, 13); ROT1(arr[14], s, 14); ROT1(arr[15], s, 15)

__device__ __forceinline__ float fmax3_(float a, float b, float c) { return fmaxf(fmaxf(a, b), c); }

// ---------------------------------------------------------------------------
// Kernel 1: emissions GEMM — UNCHANGED (bit-exact; ~45 us).
// ---------------------------------------------------------------------------
__global__ __launch_bounds__(256) void emis_kernel(const float* __restrict__ X,
                                                   const float* __restrict__ W,
                                                   const float* __restrict__ bias,
                                                   float* __restrict__ em) {
    __shared__ __align__(16) float xs[64 * 260];
    __shared__ __align__(16) float wsh[32 * 260];
    const int tid = threadIdx.x;
    const long rowbase = (long)blockIdx.x * 64;

    const float4* Xg = (const float4*)(X + rowbase * FF);
#pragma unroll
    for (int i = 0; i < 16; ++i) {
        int idx = tid + i * 256;
        int r = idx >> 6, c4 = idx & 63;
        *(float4*)&xs[r * 260 + c4 * 4] = Xg[idx];
    }
    const float4* Wg = (const float4*)W;
#pragma unroll
    for (int i = 0; i < 8; ++i) {
        int idx = tid + i * 256;
        int r = idx >> 6, c4 = idx & 63;
        *(float4*)&wsh[r * 260 + c4 * 4] = Wg[idx];
    }
    __syncthreads();

    const int rp = tid >> 3;
    const int cg = (tid & 7) * 4;
    const int r0 = rp * 2, r1 = rp * 2 + 1;
    float acc0[4] = {0.f, 0.f, 0.f, 0.f};
    float acc1[4] = {0.f, 0.f, 0.f, 0.f};

#pragma unroll 4
    for (int k = 0; k < 256; k += 4) {
        float4 xa = *(const float4*)&xs[r0 * 260 + k];
        float4 xb = *(const float4*)&xs[r1 * 260 + k];
#pragma unroll
        for (int jj = 0; jj < 4; ++jj) {
            float4 w = *(const float4*)&wsh[(cg + jj) * 260 + k];
            acc0[jj] = fmaf(xa.x, w.x, acc0[jj]);
            acc0[jj] = fmaf(xa.y, w.y, acc0[jj]);
            acc0[jj] = fmaf(xa.z, w.z, acc0[jj]);
            acc0[jj] = fmaf(xa.w, w.w, acc0[jj]);
            acc1[jj] = fmaf(xb.x, w.x, acc1[jj]);
            acc1[jj] = fmaf(xb.y, w.y, acc1[jj]);
            acc1[jj] = fmaf(xb.z, w.z, acc1[jj]);
            acc1[jj] = fmaf(xb.w, w.w, acc1[jj]);
        }
    }
#pragma unroll
    for (int jj = 0; jj < 4; ++jj) {
        float bj = bias[cg + jj];
        em[(rowbase + r0) * CC + cg + jj] = acc0[jj] + bj;
        em[(rowbase + r1) * CC + cg + jj] = acc1[jj] + bj;
    }
}

// ---------------------------------------------------------------------------
// Kernel 2: forward alpha chain — inline-asm step (33 VALU + hazard nops).
// Same math as r8: base = half-select(permlane16_swap(a)); 16 candidates via
// v_add_f32_dpp row_ror:k (+Ti[k] per probe map); exact max3 tree; cross-half
// combine via permlane32_swap; a = gv + e. Masks prebuilt via __ballot.
// e via 8-deep global register queue; alpha stored in-place over em.
// ---------------------------------------------------------------------------
#define STEP_ASM(avar, evar)                                                        \
    do {                                                                            \
        float x_, y_, b_, q0_, q1_, q2_, q3_, q4_, q5_, q6_, q7_,                   \
              q8_, q9_, q10_, q11_, q12_, q13_, q14_, q15_;                         \
        asm volatile(                                                               \
            "v_mov_b32 %[x], %[aa]\n\t"                                             \
            "s_nop 1\n\t"                                                           \
            "v_permlane16_swap_b32 %[x], %[aa]\n\t"                                 \
            "s_nop 0\n\t"                                                           \
            "v_cndmask_b32 %[bb], %[aa], %[x], %[m16]\n\t"                          \
            "s_nop 1\n\t"                                                           \
            "v_add_f32 %[q0], %[bb], %[t0]\n\t"                                     \
            "v_add_f32_dpp %[q1], %[bb], %[t1] row_ror:1 row_mask:0xf bank_mask:0xf\n\t"  \
            "v_add_f32_dpp %[q2], %[bb], %[t2] row_ror:2 row_mask:0xf bank_mask:0xf\n\t"  \
            "v_add_f32_dpp %[q3], %[bb], %[t3] row_ror:3 row_mask:0xf bank_mask:0xf\n\t"  \
            "v_add_f32_dpp %[q4], %[bb], %[t4] row_ror:4 row_mask:0xf bank_mask:0xf\n\t"  \
            "v_add_f32_dpp %[q5], %[bb], %[t5] row_ror:5 row_mask:0xf bank_mask:0xf\n\t"  \
            "v_add_f32_dpp %[q6], %[bb], %[t6] row_ror:6 row_mask:0xf bank_mask:0xf\n\t"  \
            "v_add_f32_dpp %[q7], %[bb], %[t7] row_ror:7 row_mask:0xf bank_mask:0xf\n\t"  \
            "v_add_f32_dpp %[q8], %[bb], %[t8] row_ror:8 row_mask:0xf bank_mask:0xf\n\t"  \
            "v_add_f32_dpp %[q9], %[bb], %[t9] row_ror:9 row_mask:0xf bank_mask:0xf\n\t"  \
            "v_add_f32_dpp %[q10], %[bb], %[t10] row_ror:10 row_mask:0xf bank_mask:0xf\n\t" \
            "v_add_f32_dpp %[q11], %[bb], %[t11] row_ror:11 row_mask:0xf bank_mask:0xf\n\t" \
            "v_add_f32_dpp %[q12], %[bb], %[t12] row_ror:12 row_mask:0xf bank_mask:0xf\n\t" \
            "v_add_f32_dpp %[q13], %[bb], %[t13] row_ror:13 row_mask:0xf bank_mask:0xf\n\t" \
            "v_add_f32_dpp %[q14], %[bb], %[t14] row_ror:14 row_mask:0xf bank_mask:0xf\n\t" \
            "v_add_f32_dpp %[q15], %[bb], %[t15] row_ror:15 row_mask:0xf bank_mask:0xf\n\t" \
            "v_max3_f32 %[q0], %[q0], %[q1], %[q2]\n\t"                             \
            "v_max3_f32 %[q3], %[q3], %[q4], %[q5]\n\t"                             \
            "v_max3_f32 %[q6], %[q6], %[q7], %[q8]\n\t"                             \
            "v_max3_f32 %[q9], %[q9], %[q10], %[q11]\n\t"                           \
            "v_max3_f32 %[q12], %[q12], %[q13], %[q14]\n\t"                         \
            "v_max3_f32 %[q0], %[q0], %[q3], %[q6]\n\t"                             \
            "v_max3_f32 %[q9], %[q9], %[q12], %[q15]\n\t"                           \
            "v_max_f32 %[q0], %[q0], %[q9]\n\t"                                     \
            "v_mov_b32 %[x], %[q0]\n\t"                                             \
            "v_mov_b32 %[y], %[q0]\n\t"                                             \
            "s_nop 1\n\t"                                                           \
            "v_permlane32_swap_b32 %[x], %[y]\n\t"                                  \
            "s_nop 0\n\t"                                                           \
            "v_cndmask_b32 %[y], %[y], %[x], %[m32]\n\t"                            \
            "v_max_f32 %[q0], %[q0], %[y]\n\t"                                      \
            "v_add_f32 %[aa], %[q0], %[ee]\n\t"                                     \
            : [aa] "+v"(avar), [x] "=&v"(x_), [y] "=&v"(y_), [bb] "=&v"(b_),        \
              [q0] "=&v"(q0_), [q1] "=&v"(q1_), [q2] "=&v"(q2_), [q3] "=&v"(q3_),   \
              [q4] "=&v"(q4_), [q5] "=&v"(q5_), [q6] "=&v"(q6_), [q7] "=&v"(q7_),   \
              [q8] "=&v"(q8_), [q9] "=&v"(q9_), [q10] "=&v"(q10_),                  \
              [q11] "=&v"(q11_), [q12] "=&v"(q12_), [q13] "=&v"(q13_),              \
              [q14] "=&v"(q14_), [q15] "=&v"(q15_)                                  \
            : [ee] "v"(evar), [t0] "v"(Ti[0]), [t1] "v"(Ti[1]), [t2] "v"(Ti[2]),    \
              [t3] "v"(Ti[3]), [t4] "v"(Ti[4]), [t5] "v"(Ti[5]), [t6] "v"(Ti[6]),   \
              [t7] "v"(Ti[7]), [t8] "v"(Ti[8]), [t9] "v"(Ti[9]), [t10] "v"(Ti[10]), \
              [t11] "v"(Ti[11]), [t12] "v"(Ti[12]), [t13] "v"(Ti[13]),              \
              [t14] "v"(Ti[14]), [t15] "v"(Ti[15]),                                 \
              [m16] "s"(mask16), [m32] "s"(mask32));                                \
    } while (0)

__global__ __launch_bounds__(64, 1) void viterbi_fwd4(float* __restrict__ em,
                                                      const float* __restrict__ T,
                                                      const float* __restrict__ startT,
                                                      const float* __restrict__ endT,
                                                      float* __restrict__ out) {
    const int l = threadIdx.x;
    const int b = blockIdx.x;
    const int j = l & 31;
    const int h = l >> 5;

    // probe permlane16_swap orientation -> per-lane select mask
    int p0, p1;
    plswap16(j, p0, p1);
    const bool c16 = (((p0 >> 4) & 1) == h);
    const int pm = c16 ? p0 : p1;
    int mk[16];
    ROTALL(mk, pm);
    // probe permlane32_swap orientation
    int q0, q1;
    plswap32(l, q0, q1);
    const bool pick0 = (q0 == (l ^ 32));

    const unsigned long long mask16 = __ballot(c16);
    const unsigned long long mask32 = __ballot(pick0);

    float Ti[16];
#pragma unroll
    for (int k = 0; k < 16; ++k) Ti[k] = T[mk[k] * CC + j];

    float* eb = em + (long)b * SS * CC;

    // 8-deep emission prefetch queue (e[t] lives in eq[t&7])
    float eq[8];
#pragma unroll
    for (int v = 0; v < 8; ++v) eq[v] = eb[v * 32 + j];

    float a = startT[j] + eq[0];           // alpha_0
    eb[j] = a;
    eq[0] = eb[8 * 32 + j];

    int t = 1;
    for (int g = 0; g < 254; ++g) {
#pragma unroll
        for (int u = 0; u < 8; ++u) {
            STEP_ASM(a, eq[t & 7]);
            eb[t * 32 + j] = a;
            eq[t & 7] = eb[(t + 8) * 32 + j];
            ++t;
        }
    }
#pragma unroll
    for (int u = 0; u < 7; ++u) {
        STEP_ASM(a, eq[t & 7]);
        eb[t * 32 + j] = a;
        eq[t & 7] = eb[(t + 8) * 32 + j];
        ++t;
    }
#pragma unroll
    for (int u = 0; u < 8; ++u) {
        STEP_ASM(a, eq[t & 7]);
        eb[t * 32 + j] = a;
        ++t;
    }

    // final: best_score + last tag (tie -> lowest j)
    float v = a + endT[j];
    int idx = j;
#pragma unroll
    for (int d = 1; d <= 16; d <<= 1) {
        float ovv = __shfl_xor(v, d);
        int   oii = __shfl_xor(idx, d);
        bool c = (ovv > v) || (ovv == v && oii < idx);
        v = c ? ovv : v;
        idx = c ? oii : idx;
    }
    if (l == 0) {
        out[b] = v;
        out[BB + (long)b * SS + (SS - 1)] = (float)idx;
    }
}

// ---------------------------------------------------------------------------
// Kernel 3: bp_compose — UNCHANGED from r6/r8 (recomputes bp from alphas,
// exact argmax semantics, packs, composes chunk LUT G). 2048 parallel waves.
// ---------------------------------------------------------------------------
__global__ __launch_bounds__(64, 2) void bp_compose(const float* __restrict__ alpha,
                                                    const float* __restrict__ T,
                                                    unsigned* __restrict__ bp,
                                                    unsigned char* __restrict__ G) {
    const int l = threadIdx.x;
    const int j = l & 31;
    const int h = l >> 5;
    const int b = blockIdx.x >> 5;
    const int k = blockIdx.x & 31;

    int p0, p1;
    plswap16(j, p0, p1);
    const bool c16 = (((p0 >> 4) & 1) == h);
    const int pm = c16 ? p0 : p1;
    int mk[16];
    ROTALL(mk, pm);
    int q0, q1;
    plswap32(l, q0, q1);
    const bool pick0 = (q0 == (l ^ 32));

    float Ti[16];
    unsigned Bk[16];
#pragma unroll
    for (int kk = 0; kk < 16; ++kk) {
        Ti[kk] = T[mk[kk] * CC + j];
        Bk[kk] = 1u << mk[kk];
    }

    const float* A = alpha + (long)b * SS * CC;
    const int kk0 = k << 6;

    float aq[8];
#pragma unroll
    for (int v = 0; v < 8; ++v) aq[v] = A[(kk0 + v) * CC + j];

    unsigned sr[16];
#pragma unroll
    for (int p = 0; p < 16; ++p) sr[p] = 0u;

#pragma unroll
    for (int g8 = 0; g8 < 8; ++g8) {
#pragma unroll
        for (int v = 0; v < 8; ++v) {
            const int u = g8 * 8 + v;
            float av = aq[v];
            if (g8 < 7) aq[v] = A[(kk0 + (g8 + 1) * 8 + v) * CC + j];

            int x, y;
            plswap16(__float_as_int(av), x, y);
            int base = c16 ? x : y;
            int rot[16];
            ROTALL(rot, base);
            float s[16];
#pragma unroll
            for (int kk = 0; kk < 16; ++kk) s[kk] = __int_as_float(rot[kk]) + Ti[kk];

            float m0 = fmax3_(s[0], s[1], s[2]);
            float m1 = fmax3_(s[3], s[4], s[5]);
            float m2 = fmax3_(s[6], s[7], s[8]);
            float m3 = fmax3_(s[9], s[10], s[11]);
            float m4 = fmax3_(s[12], s[13], s[14]);
            float mv = fmaxf(fmax3_(m0, m1, m2), fmax3_(m3, m4, s[15]));

            int xm, ym;
            plswap32(__float_as_int(mv), xm, ym);
            float ov = __int_as_float(pick0 ? xm : ym);
            float gv = fmaxf(mv, ov);

            unsigned c0 = (s[0] == gv) ? Bk[0] : 0u,   c1 = (s[1] == gv) ? Bk[1] : 0u;
            unsigned c2 = (s[2] == gv) ? Bk[2] : 0u,   c3 = (s[3] == gv) ? Bk[3] : 0u;
            unsigned c4 = (s[4] == gv) ? Bk[4] : 0u,   c5 = (s[5] == gv) ? Bk[5] : 0u;
            unsigned c6 = (s[6] == gv) ? Bk[6] : 0u,   c7 = (s[7] == gv) ? Bk[7] : 0u;
            unsigned c8 = (s[8] == gv) ? Bk[8] : 0u,   c9 = (s[9] == gv) ? Bk[9] : 0u;
            unsigned c10 = (s[10] == gv) ? Bk[10] : 0u, c11 = (s[11] == gv) ? Bk[11] : 0u;
            unsigned c12 = (s[12] == gv) ? Bk[12] : 0u, c13 = (s[13] == gv) ? Bk[13] : 0u;
            unsigned c14 = (s[14] == gv) ? Bk[14] : 0u, c15 = (s[15] == gv) ? Bk[15] : 0u;
            unsigned msk = ((c0 | c1 | c2) | (c3 | c4 | c5)) |
                           ((c6 | c7 | c8) | (c9 | c10 | c11)) |
                           ((c12 | c13 | c14) | c15);

            int xk, yk;
            plswap32((int)msk, xk, yk);
            unsigned om = (unsigned)(pick0 ? xk : yk);
            int wi = __builtin_ctz(msk | om);

            if (u == 63) {
                if (kk0 + 63 == SS - 1) wi = j;
            }
            sr[u >> 2] |= (unsigned)wi << ((u & 3) * 8);
        }
    }

#pragma unroll
    for (int p = 0; p < 16; ++p)
        bp[((unsigned)(16 * k + p) * BB + b) * CC + j] = sr[p];

    int g = j;
#pragma unroll
    for (int rel = 63; rel >= 0; --rel) {
        unsigned dw = (unsigned)__builtin_amdgcn_ds_bpermute((g | (l & 32)) << 2,
                                                             (int)sr[rel >> 2]);
        g = (int)((dw >> ((rel & 3) * 8)) & 31u);
    }
    G[(b * 32 + k) * 32 + j] = (unsigned char)g;
}

// ---------------------------------------------------------------------------
// Kernel 4: bt_emit2 — bt_scan folded in: each (b,chunk) block walks the
// chunk-LUT chain G[31..k+1] itself (tiny, L2-resident), then re-walks its
// 64 bp steps capturing one tag per lane.
// ---------------------------------------------------------------------------
__global__ __launch_bounds__(64) void bt_emit2(const unsigned* __restrict__ bp,
                                               const unsigned char* __restrict__ G,
                                               float* __restrict__ out) {
    const int l = threadIdx.x;
    const int b = blockIdx.x >> 5;
    const int k = blockIdx.x & 31;

    unsigned sr[16];
#pragma unroll
    for (int p = 0; p < 16; ++p) sr[p] = bp[((unsigned)(16 * k + p) * BB + b) * CC + (l & 31)];

    int cur = (int)out[BB + (long)b * SS + (SS - 1)];
    for (int kk = 31; kk > k; --kk) cur = (int)G[(b * 32 + kk) * 32 + cur];

    int g = cur, cap = cur;
#pragma unroll
    for (int rel = 63; rel >= 0; --rel) {
        unsigned dw = (unsigned)__builtin_amdgcn_ds_bpermute((g | (l & 32)) << 2,
                                                             (int)sr[rel >> 2]);
        g = (int)((dw >> ((rel & 3) * 8)) & 31u);
        cap = (l == rel) ? g : cap;
    }
    out[BB + (long)b * SS + k * 64 + l] = (float)cap;
}

// ---------------------------------------------------------------------------
extern "C" void kernel_launch(void* const* d_in, const int* in_sizes, int n_in,
                              void* d_out, int out_size, void* d_ws, size_t ws_size,
                              hipStream_t stream) {
    const float* X      = (const float*)d_in[0];
    const float* W      = (const float*)d_in[1];
    const float* bias   = (const float*)d_in[2];
    const float* T      = (const float*)d_in[3];
    const float* startT = (const float*)d_in[4];
    const float* endT   = (const float*)d_in[5];
    float* out = (float*)d_out;

    float*    em = (float*)d_ws;                                        // 16 MB (e -> alpha in-place)
    unsigned* bp = (unsigned*)((char*)d_ws + (size_t)BB * SS * CC * 4); // 4 MB @ 16 MB
    unsigned char* G = (unsigned char*)d_ws + (20u << 20);              // 64 KB @ 20 MB

    emis_kernel<<<(BB * SS) / 64, 256, 0, stream>>>(X, W, bias, em);
    viterbi_fwd4<<<BB, 64, 0, stream>>>(em, T, startT, endT, out);
    bp_compose<<<BB * 32, 64, 0, stream>>>(em, T, bp, G);
    bt_emit2<<<BB * 32, 64, 0, stream>>>(bp, G, out);
}